// Round 3
// baseline (576.080 us; speedup 1.0000x reference)
//
#include <hip/hip_runtime.h>
#include <stdint.h>

// FreeConv2D: B=64,H=W=64,C=64, U=64,K=5,S=2 -> OH=OW=30
// One block per (oh,ow): GEMM M=64(b) x N=64(u) x K=1600, bf16 MFMA, fp32 accum.
// R3: staging via global_load_lds (width=16) fp32 DMA, K-chunk=64, 32 KB LDS,
//     5 blocks/CU, cvt fp32->bf16 on the LDS->reg frag read. HBM-bound target.

typedef __bf16 bf16x8 __attribute__((ext_vector_type(8)));
typedef float f32x4 __attribute__((ext_vector_type(4)));

typedef __attribute__((address_space(1))) uint32_t glob_u32;
typedef __attribute__((address_space(3))) uint32_t lds_u32;

__device__ __forceinline__ void dma16(const void* g, void* l) {
    __builtin_amdgcn_global_load_lds(
        (const glob_u32*)(uintptr_t)g,
        (lds_u32*)(uint32_t)(uintptr_t)l,   // low 32 bits of generic LDS ptr = LDS offset
        16, 0, 0);
}

__device__ __forceinline__ unsigned brne(unsigned a) {   // fp32 bits -> rounded (RNE) in high 16
    return a + 0x7FFFu + ((a >> 16) & 1u);
}

// LDS chunk layout (fp32, K-chunk=64, 4096 f32 = 16 KB per matrix):
//   idx(m,kk) = ((kk>>5)*4 + (m>>4))*512 + ((kk>>2)&1)*256 + ((kk>>3)&3)*64 + (m&15)*4 + (kk&3)
// DMA slot s, wave wv: f32 index fi = wv*1024 + s*256 + lane*4 -> lane stages (m, kk..kk+3),
//   global side: 16 rows x one 64B-aligned line per instr (perfect coalescing).
// Frag read (ks,tile), lane l: two b128 at blk*512 + h*256 + (l>>4)*64 + (l&15)*4, h=0,1
//   -> 8 words/bank uniform (conflict-free).

__device__ __forceinline__ bf16x8 cvt_frag(const float* p) {
    const uint4 a = *(const uint4*)p;          // j = 0..3
    const uint4 b = *(const uint4*)(p + 256);  // j = 4..7
    union { unsigned u[4]; bf16x8 v; } r;
    r.u[0] = __builtin_amdgcn_perm(brne(a.y), brne(a.x), 0x07060302);
    r.u[1] = __builtin_amdgcn_perm(brne(a.w), brne(a.z), 0x07060302);
    r.u[2] = __builtin_amdgcn_perm(brne(b.y), brne(b.x), 0x07060302);
    r.u[3] = __builtin_amdgcn_perm(brne(b.w), brne(b.z), 0x07060302);
    return r.v;
}

__global__ __launch_bounds__(256)
void freeconv_kernel(const float* __restrict__ x,
                     const float* __restrict__ w,
                     const float* __restrict__ bias,
                     float* __restrict__ out) {
    __shared__ __align__(16) float ldsA[4096];   // x-window chunk: 64 x 64 fp32
    __shared__ __align__(16) float ldsB[4096];   // weight chunk:   64 x 64 fp32

    const int bid = blockIdx.x;
    const int oh = bid / 30;
    const int ow = bid - oh * 30;
    const int t = threadIdx.x;
    const int lane = t & 63;
    const int wv = t >> 6;
    const int wvu = __builtin_amdgcn_readfirstlane(wv);  // uniform wave id for LDS DMA base
    const int wm = wv >> 1;   // m rows [wm*32, wm*32+32)
    const int wn = wv & 1;    // n cols [wn*32, wn*32+32)

    // DMA slot decode -> per-lane global row/col offsets (constant across chunks)
    int ia[4], ib[4];
#pragma unroll
    for (int s = 0; s < 4; ++s) {
        int fi = wv * 1024 + s * 256 + lane * 4;
        int blk = fi >> 9;
        int half = (fi >> 8) & 1;
        int grp = (fi >> 6) & 3;
        int mi = (fi >> 2) & 15;
        int m = (blk & 3) * 16 + mi;
        int kk = (blk >> 2) * 32 + grp * 8 + half * 4;
        ia[s] = m * 262144 + kk;   // x: batch stride 64*64*64
        ib[s] = m * 1600 + kk;     // w: u stride 5*5*64
    }

    f32x4 acc[2][2];
#pragma unroll
    for (int a = 0; a < 2; ++a)
#pragma unroll
        for (int b = 0; b < 2; ++b)
#pragma unroll
            for (int r = 0; r < 4; ++r) acc[a][b][r] = 0.f;

    const float* wblk = w + (oh * 30 + ow) * 102400;
    float* lA = ldsA + wvu * 1024;
    float* lB = ldsB + wvu * 1024;

    for (int i = 0; i < 5; ++i) {
        const float* pa_i = x + (oh * 2 + i) * 4096 + ow * 128;
        const float* pb_i = wblk + i * 320;
        for (int kh = 0; kh < 5; ++kh) {
            const float* pa = pa_i + kh * 64;
            const float* pb = pb_i + kh * 64;
#pragma unroll
            for (int s = 0; s < 4; ++s) {
                dma16(pa + ia[s], lA + s * 256);
                dma16(pb + ib[s], lB + s * 256);
            }
            __syncthreads();   // drains vmcnt incl. DMA

#pragma unroll
            for (int ks = 0; ks < 2; ++ks) {
                const int rbase = (lane >> 4) * 64 + (lane & 15) * 4;
                const bf16x8 a0 = cvt_frag(ldsA + (ks * 4 + wm * 2 + 0) * 512 + rbase);
                const bf16x8 a1 = cvt_frag(ldsA + (ks * 4 + wm * 2 + 1) * 512 + rbase);
                const bf16x8 b0 = cvt_frag(ldsB + (ks * 4 + wn * 2 + 0) * 512 + rbase);
                const bf16x8 b1 = cvt_frag(ldsB + (ks * 4 + wn * 2 + 1) * 512 + rbase);
                acc[0][0] = __builtin_amdgcn_mfma_f32_16x16x32_bf16(a0, b0, acc[0][0], 0, 0, 0);
                acc[0][1] = __builtin_amdgcn_mfma_f32_16x16x32_bf16(a0, b1, acc[0][1], 0, 0, 0);
                acc[1][0] = __builtin_amdgcn_mfma_f32_16x16x32_bf16(a1, b0, acc[1][0], 0, 0, 0);
                acc[1][1] = __builtin_amdgcn_mfma_f32_16x16x32_bf16(a1, b1, acc[1][1], 0, 0, 0);
            }
            __syncthreads();   // protect LDS from next chunk's DMA
        }
    }

    // epilogue: C/D layout col=lane&15, row=(lane>>4)*4+reg; add bias; store fp32
    const float* bp = bias + (oh * 30 + ow) * 64;
    const int col = lane & 15;
    const int r0 = (lane >> 4) * 4;
    const float bv0 = bp[wn * 32 + col];
    const float bv1 = bp[wn * 32 + 16 + col];
#pragma unroll
    for (int ms = 0; ms < 2; ++ms) {
#pragma unroll
        for (int r = 0; r < 4; ++r) {
            int bi = wm * 32 + ms * 16 + r0 + r;   // batch index
            float* op = out + ((bi * 30 + oh) * 30 + ow) * 64 + wn * 32 + col;
            op[0]  = acc[ms][0][r] + bv0;
            op[16] = acc[ms][1][r] + bv1;
        }
    }
}

extern "C" void kernel_launch(void* const* d_in, const int* in_sizes, int n_in,
                              void* d_out, int out_size, void* d_ws, size_t ws_size,
                              hipStream_t stream) {
    const float* x = (const float*)d_in[0];
    const float* w = (const float*)d_in[1];
    const float* b = (const float*)d_in[2];
    float* out = (float*)d_out;
    (void)in_sizes; (void)n_in; (void)out_size; (void)d_ws; (void)ws_size;
    freeconv_kernel<<<dim3(900), dim3(256), 0, stream>>>(x, w, b, out);
}